// Round 1
// baseline (1603.025 us; speedup 1.0000x reference)
//
#include <hip/hip_runtime.h>

#define NN 8192
#define FF 64
#define INF 48
#define NCLS 16

// ws layout (floats):
// h:     [0, 524288)
// s1:    [524288, +8192)
// s2, g, M, den, ci(int), cmax(u32 x16)

__device__ __forceinline__ float lrelu(float x) { return fmaxf(x, 0.2f * x); }

// Kernel A: h = in@W, s1 = h@a1, s2 = h@a2, classes, per-class s1 max (encoded atomicMax)
__global__ __launch_bounds__(256) void kA(const float* __restrict__ in,
                                          const float* __restrict__ W,
                                          const float* __restrict__ a,
                                          const int* __restrict__ labels,
                                          float* __restrict__ h,
                                          float* __restrict__ s1,
                                          float* __restrict__ s2,
                                          int* __restrict__ ci,
                                          unsigned int* __restrict__ cmax) {
  __shared__ float sIn[4][INF];
  int t = threadIdx.x;
  int w = t >> 6, lane = t & 63;
  int i = blockIdx.x * 4 + w;
  if (lane < INF) sIn[w][lane] = in[i * INF + lane];
  __syncthreads();
  float acc = 0.f;
#pragma unroll
  for (int k = 0; k < INF; k++) acc += sIn[w][k] * W[k * FF + lane];
  h[i * FF + lane] = acc;
  float v1 = acc * a[lane];
  float v2 = acc * a[FF + lane];
#pragma unroll
  for (int off = 32; off > 0; off >>= 1) {
    v1 += __shfl_xor(v1, off, 64);
    v2 += __shfl_xor(v2, off, 64);
  }
  if (lane == 0) {
    s1[i] = v1;
    s2[i] = v2;
    int c = labels[i] - 1;
    c = c < 0 ? 0 : (c > 15 ? 15 : c);
    ci[i] = c;
    unsigned int u = __float_as_uint(v1);
    u = (u & 0x80000000u) ? ~u : (u | 0x80000000u);
    atomicMax(&cmax[c], u);
  }
}

// Kernel B: per column j, exact M[j] via 16 class maxima (leaky monotone), then
// denom[j] partial sums over an i-segment (8 segments, atomicAdd).
__global__ __launch_bounds__(256) void kB(const float* __restrict__ s1,
                                          const float* __restrict__ s2,
                                          const int* __restrict__ ci,
                                          const float* __restrict__ Bmat,
                                          const float* __restrict__ alpha_p,
                                          const unsigned int* __restrict__ cmax,
                                          float* __restrict__ Mout,
                                          float* __restrict__ den) {
  __shared__ float Bs[256];
  __shared__ float cm[16];
  __shared__ float s1s[256];
  __shared__ int cis[256];
  int t = threadIdx.x;
  float alpha = alpha_p[0];
  Bs[t] = alpha * Bmat[t];
  if (t < 16) {
    unsigned int u = cmax[t];
    float f;
    if (u == 0u) f = -1e30f;  // empty class (class 15 is always empty)
    else f = (u & 0x80000000u) ? __uint_as_float(u ^ 0x80000000u) : __uint_as_float(~u);
    cm[t] = f;
  }
  __syncthreads();
  int jb = blockIdx.x & 31;
  int seg = blockIdx.x >> 5;
  int j = jb * 256 + t;
  float s2j = s2[j];
  int cj = ci[j];
  float Mj = -1e30f;
#pragma unroll
  for (int c = 0; c < 16; c++) Mj = fmaxf(Mj, lrelu(cm[c] + s2j) + Bs[c * 16 + cj]);
  float acc = 0.f;
  int i0 = seg * 1024;
  for (int ch = 0; ch < 4; ch++) {
    __syncthreads();
    s1s[t] = s1[i0 + ch * 256 + t];
    cis[t] = ci[i0 + ch * 256 + t];
    __syncthreads();
#pragma unroll 4
    for (int k = 0; k < 256; k++) {
      float x = s1s[k] + s2j;
      float e = lrelu(x) + Bs[cis[k] * 16 + cj] - Mj;
      acc += __expf(e);
    }
  }
  atomicAdd(&den[j], acc);
  if (seg == 0) Mout[j] = Mj;
}

__global__ __launch_bounds__(256) void kB2(const float* __restrict__ M,
                                           const float* __restrict__ den,
                                           float* __restrict__ g) {
  int j = blockIdx.x * 256 + threadIdx.x;
  g[j] = __expf(-M[j]) / den[j];
}

// Kernel C: out = elu(attention @ h). 256 blocks, tile = 32 rows x 64 feats.
// Attention tile (32 x 128) generated on the fly into LDS, then fp32 MAC with
// float4 broadcast LDS reads; h read through L1/L2 (2 MB, L2-resident).
__global__ __launch_bounds__(256) void kC(const float* __restrict__ h,
                                          const float* __restrict__ s1,
                                          const float* __restrict__ s2,
                                          const float* __restrict__ g,
                                          const int* __restrict__ ci,
                                          const float* __restrict__ Bmat,
                                          const float* __restrict__ alpha_p,
                                          float* __restrict__ out) {
  __shared__ __align__(16) float A[32 * 128];  // [jj][row], row-fast for float4 reads
  __shared__ float Bs[256];
  __shared__ float s1r[32];
  __shared__ int cir[32];
  __shared__ float s2c[128];
  __shared__ float gc[128];
  __shared__ int cjc[128];
  int t = threadIdx.x;
  int f = t & 63, iq = t >> 6;
  int bi = blockIdx.x * 32;
  float alpha = alpha_p[0];
  Bs[t] = alpha * Bmat[t];
  if (t < 32) {
    s1r[t] = s1[bi + t];
    cir[t] = ci[bi + t];
  }
  float acc[8] = {0.f, 0.f, 0.f, 0.f, 0.f, 0.f, 0.f, 0.f};
  for (int j0 = 0; j0 < NN; j0 += 128) {
    __syncthreads();
    if (t < 128) {
      s2c[t] = s2[j0 + t];
      gc[t] = g[j0 + t];
      cjc[t] = ci[j0 + t];
    }
    __syncthreads();
    // generate A tile: 4096 entries / 256 threads = 16 each, coalesced LDS writes
#pragma unroll
    for (int k = 0; k < 16; k++) {
      int v = t + 256 * k;
      int jj = v >> 5, row = v & 31;
      float x = s1r[row] + s2c[jj];
      float e = lrelu(x) + Bs[cir[row] * 16 + cjc[jj]];
      A[v] = __expf(e) * gc[jj];
    }
    __syncthreads();
    const float* hp = &h[j0 * FF + f];
#pragma unroll 2
    for (int jj = 0; jj < 128; jj++) {
      float hv = hp[jj * FF];
      const float4* ap = (const float4*)&A[jj * 32 + iq * 8];
      float4 a0 = ap[0], a1 = ap[1];
      acc[0] += a0.x * hv;
      acc[1] += a0.y * hv;
      acc[2] += a0.z * hv;
      acc[3] += a0.w * hv;
      acc[4] += a1.x * hv;
      acc[5] += a1.y * hv;
      acc[6] += a1.z * hv;
      acc[7] += a1.w * hv;
    }
  }
#pragma unroll
  for (int r = 0; r < 8; r++) {
    float v = acc[r];
    out[(bi + iq * 8 + r) * FF + f] = v > 0.f ? v : __expf(v) - 1.f;
  }
}

extern "C" void kernel_launch(void* const* d_in, const int* in_sizes, int n_in,
                              void* d_out, int out_size, void* d_ws, size_t ws_size,
                              hipStream_t stream) {
  const float* in = (const float*)d_in[0];
  // d_in[1] = adj (all-ones, unused by reference math) — never touched
  const float* W = (const float*)d_in[2];
  const float* a = (const float*)d_in[3];
  const float* Bmat = (const float*)d_in[4];
  const float* alpha = (const float*)d_in[5];
  const int* labels = (const int*)d_in[6];
  float* out = (float*)d_out;

  float* ws = (float*)d_ws;
  float* h = ws;                    // 524288
  float* s1 = ws + 524288;          // 8192
  float* s2 = s1 + 8192;            // 8192
  float* g = s2 + 8192;             // 8192
  float* M = g + 8192;              // 8192
  float* den = M + 8192;            // 8192
  int* ci = (int*)(den + 8192);     // 8192
  unsigned int* cmax = (unsigned int*)(ci + 8192);  // 16

  hipMemsetAsync(den, 0, 8192 * sizeof(float), stream);
  hipMemsetAsync(cmax, 0, 16 * sizeof(unsigned int), stream);

  kA<<<2048, 256, 0, stream>>>(in, W, a, labels, h, s1, s2, ci, cmax);
  kB<<<256, 256, 0, stream>>>(s1, s2, ci, Bmat, alpha, cmax, M, den);
  kB2<<<32, 256, 0, stream>>>(M, den, g);
  kC<<<256, 256, 0, stream>>>(h, s1, s2, g, ci, Bmat, alpha, out);
}

// Round 3
// 525.407 us; speedup vs baseline: 3.0510x; 3.0510x over previous
//
#include <hip/hip_runtime.h>
#include <hip/hip_bf16.h>

#define NN 8192
#define FF 64
#define INF 48
#define NP 8704   // padded column count: 16 buckets, each 32-aligned (max 8192+16*31=8688)
#define NCH (NP/32)  // 272 chunks
#define LOG2E 1.4426950408889634f

typedef __attribute__((ext_vector_type(8))) short short8;
typedef __attribute__((ext_vector_type(4))) float f32x4;

__device__ __forceinline__ float fexp2(float x) { return __builtin_amdgcn_exp2f(x); }

__device__ __forceinline__ unsigned int packbf2(float a, float b) {
  union { __hip_bfloat162 h2; unsigned int u; } c;
  c.h2 = __float22bfloat162_rn(float2{a, b});
  return c.u;
}
__device__ __forceinline__ unsigned short packbf1(float a) {
  union { __hip_bfloat16 h; unsigned short u; } c;
  c.h = __float2bfloat16(a);
  return c.u;
}

// ---- kInit: pad defaults for permuted arrays ----
__global__ __launch_bounds__(256) void kInit(float* __restrict__ s1p, float* __restrict__ s2p,
                                             int* __restrict__ perm, int* __restrict__ clsc) {
  int jp = blockIdx.x * 256 + threadIdx.x;
  if (jp < NP) { s1p[jp] = -100.f; s2p[jp] = -100.f; perm[jp] = -1; }
  if (blockIdx.x == 0 && threadIdx.x < NCH) clsc[threadIdx.x] = 0;
}

// ---- kA: h = in@W; s1,s2 (in exp2 domain); class ci; class histogram ----
__global__ __launch_bounds__(256) void kA(const float* __restrict__ in,
                                          const float* __restrict__ W,
                                          const float* __restrict__ a,
                                          const int* __restrict__ labels,
                                          float* __restrict__ h,
                                          float* __restrict__ s1,
                                          float* __restrict__ s2,
                                          int* __restrict__ ci,
                                          int* __restrict__ hist) {
  __shared__ float sIn[4][INF];
  int t = threadIdx.x;
  int w = t >> 6, lane = t & 63;
  int i = blockIdx.x * 4 + w;
  if (lane < INF) sIn[w][lane] = in[i * INF + lane];
  __syncthreads();
  float acc = 0.f;
#pragma unroll
  for (int k = 0; k < INF; k++) acc += sIn[w][k] * W[k * FF + lane];
  h[i * FF + lane] = acc;
  float v1 = acc * a[lane];
  float v2 = acc * a[FF + lane];
#pragma unroll
  for (int off = 32; off > 0; off >>= 1) {
    v1 += __shfl_xor(v1, off, 64);
    v2 += __shfl_xor(v2, off, 64);
  }
  if (lane == 0) {
    s1[i] = v1 * LOG2E;
    s2[i] = v2 * LOG2E;
    int c = labels[i] - 1;
    c = c < 0 ? 0 : (c > 15 ? 15 : c);
    ci[i] = c;
    atomicAdd(&hist[c], 1);
  }
}

// ---- kP1: bucket starts (32-padded) -> cursors ----
__global__ void kP1(const int* __restrict__ hist, int* __restrict__ cursor) {
  if (threadIdx.x == 0) {
    int s = 0;
    for (int b = 0; b < 16; b++) { cursor[b] = s; s += (hist[b] + 31) & ~31; }
  }
}

// ---- kS: scatter into class-sorted padded order ----
__global__ __launch_bounds__(256) void kS(const float* __restrict__ s1,
                                          const float* __restrict__ s2,
                                          const int* __restrict__ ci,
                                          int* __restrict__ cursor,
                                          int* __restrict__ perm,
                                          float* __restrict__ s1p,
                                          float* __restrict__ s2p,
                                          int* __restrict__ clsc) {
  int i = blockIdx.x * 256 + threadIdx.x;
  int c = ci[i];
  int pos = atomicAdd(&cursor[c], 1);
  perm[pos] = i;
  s1p[pos] = s1[i];
  s2p[pos] = s2[i];
  clsc[pos >> 5] = c;  // benign same-value race within a chunk (buckets 32-aligned)
}

// ---- kD: Dp[jp] = sum_i exp(lrelu(s1_i + s2_jp)) * exp(alpha*B[ci,cj]), class-chunked rows ----
__global__ __launch_bounds__(256) void kD(const float* __restrict__ s1p,
                                          const float* __restrict__ s2p,
                                          const int* __restrict__ clsc,
                                          const float* __restrict__ Bmat,
                                          const float* __restrict__ alpha_p,
                                          float* __restrict__ Dp) {
  __shared__ float EBT[256];   // EBT[a*16+b] = exp(alpha*B[a][b]); a uniform per chunk, b=cj per lane -> conflict-free
  __shared__ float s1s[256];
  __shared__ int clscs[8];
  int t = threadIdx.x;
  int rs = blockIdx.y;  // row segment: 256 rows = 8 chunks
  EBT[t] = __expf(alpha_p[0] * Bmat[t]);
  s1s[t] = s1p[rs * 256 + t];
  if (t < 8) clscs[t] = clsc[rs * 8 + t];
  __syncthreads();
  int jp = blockIdx.x * 256 + t;
  float s2j = s2p[jp];
  int cj = clsc[jp >> 5];
  float acc = 0.f;
#pragma unroll
  for (int cc = 0; cc < 8; cc++) {
    float w = EBT[clscs[cc] * 16 + cj];
    float part = 0.f;
#pragma unroll
    for (int r = 0; r < 32; r++) {
      float x = s1s[cc * 32 + r] + s2j;
      part += fexp2(fmaxf(x, 0.2f * x));
    }
    acc = fmaf(part, w, acc);
  }
  atomicAdd(&Dp[jp], acc);
}

// ---- kE: h2T[f][jp] = bf16( h[perm[jp]][f] / Dp[jp] ), 0 for pads ----
__global__ __launch_bounds__(256) void kE(const float* __restrict__ h,
                                          const float* __restrict__ Dp,
                                          const int* __restrict__ perm,
                                          unsigned short* __restrict__ h2T) {
  int t = threadIdx.x;
  int jp = blockIdx.x * 256 + t;
  int fq = blockIdx.y;  // 16 quads of 4 features
  int p = perm[jp];
  if (p < 0) {
#pragma unroll
    for (int k = 0; k < 4; k++) h2T[(size_t)(fq * 4 + k) * NP + jp] = 0;
  } else {
    float g = 1.0f / Dp[jp];
    float4 hv = *(const float4*)&h[p * FF + fq * 4];
    h2T[(size_t)(fq * 4 + 0) * NP + jp] = packbf1(g * hv.x);
    h2T[(size_t)(fq * 4 + 1) * NP + jp] = packbf1(g * hv.y);
    h2T[(size_t)(fq * 4 + 2) * NP + jp] = packbf1(g * hv.z);
    h2T[(size_t)(fq * 4 + 3) * NP + jp] = packbf1(g * hv.w);
  }
}

// ---- kF: U += E_tile @ h2T^T via MFMA; E generated in A-frag register layout ----
__global__ __launch_bounds__(256) void kF(const float* __restrict__ s1,
                                          const int* __restrict__ ci,
                                          const float* __restrict__ s2p,
                                          const int* __restrict__ clsc,
                                          const unsigned short* __restrict__ h2T,
                                          const float* __restrict__ Bmat,
                                          const float* __restrict__ alpha_p,
                                          float* __restrict__ U) {
  __shared__ float EBT2[256];  // EBT2[b*16+a] = exp(alpha*B[a][b]); b uniform per chunk, a=ci per lane -> conflict-free
  int t = threadIdx.x;
  int wave = t >> 6, lane = t & 63;
  int quad = lane >> 4, l16 = lane & 15;
  EBT2[t] = __expf(alpha_p[0] * Bmat[(t & 15) * 16 + (t >> 4)]);
  int row0 = blockIdx.x * 64 + wave * 16;
  float s1v = s1[row0 + l16];
  int civ = ci[row0 + l16];
  __syncthreads();

  f32x4 acc0 = {0.f, 0.f, 0.f, 0.f};
  f32x4 acc1 = {0.f, 0.f, 0.f, 0.f};
  f32x4 acc2 = {0.f, 0.f, 0.f, 0.f};
  f32x4 acc3 = {0.f, 0.f, 0.f, 0.f};

  int jbeg = blockIdx.y * (NP / 8);
  int jend = jbeg + (NP / 8);
  for (int j0 = jbeg; j0 < jend; j0 += 32) {
    int cch = clsc[j0 >> 5];                 // uniform -> scalar load
    float w = EBT2[cch * 16 + civ];
    float4 sa = *(const float4*)&s2p[j0 + quad * 8];
    float4 sb = *(const float4*)&s2p[j0 + quad * 8 + 4];
    float e0, e1, e2, e3, e4, e5, e6, e7, x;
    x = s1v + sa.x; e0 = fexp2(fmaxf(x, 0.2f * x)) * w;
    x = s1v + sa.y; e1 = fexp2(fmaxf(x, 0.2f * x)) * w;
    x = s1v + sa.z; e2 = fexp2(fmaxf(x, 0.2f * x)) * w;
    x = s1v + sa.w; e3 = fexp2(fmaxf(x, 0.2f * x)) * w;
    x = s1v + sb.x; e4 = fexp2(fmaxf(x, 0.2f * x)) * w;
    x = s1v + sb.y; e5 = fexp2(fmaxf(x, 0.2f * x)) * w;
    x = s1v + sb.z; e6 = fexp2(fmaxf(x, 0.2f * x)) * w;
    x = s1v + sb.w; e7 = fexp2(fmaxf(x, 0.2f * x)) * w;
    union { short8 s; unsigned int u[4]; } af;
    af.u[0] = packbf2(e0, e1);
    af.u[1] = packbf2(e2, e3);
    af.u[2] = packbf2(e4, e5);
    af.u[3] = packbf2(e6, e7);
    const unsigned short* bbase = h2T + (size_t)l16 * NP + j0 + quad * 8;
    short8 b0 = *(const short8*)(bbase);
    short8 b1 = *(const short8*)(bbase + 16 * NP);
    short8 b2 = *(const short8*)(bbase + 32 * NP);
    short8 b3 = *(const short8*)(bbase + 48 * NP);
    acc0 = __builtin_amdgcn_mfma_f32_16x16x32_bf16(af.s, b0, acc0, 0, 0, 0);
    acc1 = __builtin_amdgcn_mfma_f32_16x16x32_bf16(af.s, b1, acc1, 0, 0, 0);
    acc2 = __builtin_amdgcn_mfma_f32_16x16x32_bf16(af.s, b2, acc2, 0, 0, 0);
    acc3 = __builtin_amdgcn_mfma_f32_16x16x32_bf16(af.s, b3, acc3, 0, 0, 0);
  }
  // C layout: col = lane&15, row = quad*4 + reg
#pragma unroll
  for (int reg = 0; reg < 4; reg++) {
    int ro = (row0 + quad * 4 + reg) * FF + l16;
    atomicAdd(&U[ro + 0], acc0[reg]);
    atomicAdd(&U[ro + 16], acc1[reg]);
    atomicAdd(&U[ro + 32], acc2[reg]);
    atomicAdd(&U[ro + 48], acc3[reg]);
  }
}

// ---- kG: out = elu(U) ----
__global__ __launch_bounds__(256) void kG(const float* __restrict__ U, float* __restrict__ out) {
  int idx = blockIdx.x * 256 + threadIdx.x;
  float4 v = ((const float4*)U)[idx];
  v.x = v.x > 0.f ? v.x : __expf(v.x) - 1.f;
  v.y = v.y > 0.f ? v.y : __expf(v.y) - 1.f;
  v.z = v.z > 0.f ? v.z : __expf(v.z) - 1.f;
  v.w = v.w > 0.f ? v.w : __expf(v.w) - 1.f;
  ((float4*)out)[idx] = v;
}

extern "C" void kernel_launch(void* const* d_in, const int* in_sizes, int n_in,
                              void* d_out, int out_size, void* d_ws, size_t ws_size,
                              hipStream_t stream) {
  const float* in = (const float*)d_in[0];
  // d_in[1] = adj: all-ones, mathematically unused
  const float* W = (const float*)d_in[2];
  const float* a = (const float*)d_in[3];
  const float* Bmat = (const float*)d_in[4];
  const float* alpha = (const float*)d_in[5];
  const int* labels = (const int*)d_in[6];
  float* out = (float*)d_out;

  float* ws = (float*)d_ws;
  float* h = ws;                         // 524288
  float* U = h + 524288;                 // 524288
  float* s1 = U + 524288;                // 8192
  float* s2 = s1 + 8192;                 // 8192
  int* ci = (int*)(s2 + 8192);           // 8192
  float* s1p = (float*)(ci + 8192);      // 8704
  float* s2p = s1p + NP;                 // 8704
  float* Dp = s2p + NP;                  // 8704
  int* perm = (int*)(Dp + NP);           // 8704
  int* clsc = perm + NP;                 // 272
  int* hist = clsc + NCH;                // 16
  int* cursor = hist + 16;               // 16
  unsigned short* h2T = (unsigned short*)(cursor + 16);  // 64*8704 bf16 (16B-aligned)

  (void)hipMemsetAsync(U, 0, 524288 * sizeof(float), stream);
  (void)hipMemsetAsync(Dp, 0, NP * sizeof(float), stream);
  (void)hipMemsetAsync(hist, 0, 32 * sizeof(int), stream);

  kInit<<<34, 256, 0, stream>>>(s1p, s2p, perm, clsc);
  kA<<<2048, 256, 0, stream>>>(in, W, a, labels, h, s1, s2, ci, hist);
  kP1<<<1, 64, 0, stream>>>(hist, cursor);
  kS<<<32, 256, 0, stream>>>(s1, s2, ci, cursor, perm, s1p, s2p, clsc);
  kD<<<dim3(34, 34), 256, 0, stream>>>(s1p, s2p, clsc, Bmat, alpha, Dp);
  kE<<<dim3(34, 16), 256, 0, stream>>>(h, Dp, perm, h2T);
  kF<<<dim3(128, 8), 256, 0, stream>>>(s1, ci, s2p, clsc, h2T, Bmat, alpha, U);
  kG<<<512, 256, 0, stream>>>(U, out);
}

// Round 4
// 431.074 us; speedup vs baseline: 3.7187x; 1.2188x over previous
//
#include <hip/hip_runtime.h>
#include <hip/hip_bf16.h>

#define NN 8192
#define FF 64
#define INF 48
#define NP 8704   // padded column count: 16 buckets, each 32-aligned (max 8192+16*31=8688)
#define NCH (NP/32)  // 272 chunks
#define LOG2E 1.4426950408889634f

typedef __attribute__((ext_vector_type(8))) short short8;
typedef __attribute__((ext_vector_type(4))) float f32x4;

__device__ __forceinline__ float fexp2(float x) { return __builtin_amdgcn_exp2f(x); }

__device__ __forceinline__ unsigned int packbf2(float a, float b) {
  union { __hip_bfloat162 h2; unsigned int u; } c;
  c.h2 = __float22bfloat162_rn(float2{a, b});
  return c.u;
}
__device__ __forceinline__ unsigned short packbf1(float a) {
  union { __hip_bfloat16 h; unsigned short u; } c;
  c.h = __float2bfloat16(a);
  return c.u;
}

// ---- kZ: all zero-init / pad defaults in one dispatch (no hipMemsetAsync) ----
__global__ __launch_bounds__(256) void kZ(float4* __restrict__ U4,
                                          float* __restrict__ s1p, float* __restrict__ s2p,
                                          int* __restrict__ perm, float* __restrict__ Dp,
                                          int* __restrict__ clsc) {
  int idx = blockIdx.x * 256 + threadIdx.x;
  U4[idx] = float4{0.f, 0.f, 0.f, 0.f};  // 512*256 threads * 16B = 2 MB
  if (idx < NP) { s1p[idx] = -100.f; s2p[idx] = -100.f; perm[idx] = -1; Dp[idx] = 0.f; }
  if (idx < NCH) clsc[idx] = 0;
}

// ---- kA: h = in@W; s1,s2 (exp2 domain); class ci ----
__global__ __launch_bounds__(256) void kA(const float* __restrict__ in,
                                          const float* __restrict__ W,
                                          const float* __restrict__ a,
                                          const int* __restrict__ labels,
                                          float* __restrict__ h,
                                          float* __restrict__ s1,
                                          float* __restrict__ s2,
                                          int* __restrict__ ci) {
  __shared__ float sIn[4][INF];
  int t = threadIdx.x;
  int w = t >> 6, lane = t & 63;
  int i = blockIdx.x * 4 + w;
  if (lane < INF) sIn[w][lane] = in[i * INF + lane];
  __syncthreads();
  float acc = 0.f;
#pragma unroll
  for (int k = 0; k < INF; k++) acc += sIn[w][k] * W[k * FF + lane];
  h[i * FF + lane] = acc;
  float v1 = acc * a[lane];
  float v2 = acc * a[FF + lane];
#pragma unroll
  for (int off = 32; off > 0; off >>= 1) {
    v1 += __shfl_xor(v1, off, 64);
    v2 += __shfl_xor(v2, off, 64);
  }
  if (lane == 0) {
    s1[i] = v1 * LOG2E;
    s2[i] = v2 * LOG2E;
    int c = labels[i] - 1;
    ci[i] = c < 0 ? 0 : (c > 15 ? 15 : c);
  }
}

// ---- kSort: single-block ballot-rank counting sort into 32-padded class buckets.
// No global atomics; within-class order unimportant (all downstream sums are
// order-independent).
__global__ __launch_bounds__(1024) void kSort(const float* __restrict__ s1,
                                              const float* __restrict__ s2,
                                              const int* __restrict__ ci,
                                              int* __restrict__ perm,
                                              float* __restrict__ s1p,
                                              float* __restrict__ s2p,
                                              int* __restrict__ clsc) {
  __shared__ int wcnt[16][16];   // [wave][cls] counts
  __shared__ int wbase[16][16];  // exclusive prefix over waves, per cls
  __shared__ int tot[16];        // per-class totals
  __shared__ int cbase[16];      // 32-padded class starts
  int t = threadIdx.x;
  int wv = t >> 6, lane = t & 63;
  unsigned long long lower = (1ULL << lane) - 1;  // lane=0 -> 0
  int c[8], myoff[8];
  float v1[8], v2[8];
#pragma unroll
  for (int k = 0; k < 8; k++) {
    int i = wv * 512 + k * 64 + lane;
    c[k] = ci[i];
    v1[k] = s1[i];
    v2[k] = s2[i];
  }
#pragma unroll 1
  for (int cls = 0; cls < 16; cls++) {
    int run = 0;
#pragma unroll
    for (int k = 0; k < 8; k++) {
      unsigned long long m = __ballot(c[k] == cls);
      if (c[k] == cls) myoff[k] = run + __popcll(m & lower);
      run += __popcll(m);
    }
    if (lane == 0) wcnt[wv][cls] = run;
  }
  __syncthreads();
  if (t < 16) {  // t = class
    int s = 0;
    for (int w = 0; w < 16; w++) { wbase[w][t] = s; s += wcnt[w][t]; }
    tot[t] = s;
  }
  __syncthreads();
  if (t == 0) {
    int s = 0;
    for (int cls = 0; cls < 16; cls++) { cbase[cls] = s; s += (tot[cls] + 31) & ~31; }
  }
  __syncthreads();
#pragma unroll
  for (int k = 0; k < 8; k++) {
    int i = wv * 512 + k * 64 + lane;
    int pos = cbase[c[k]] + wbase[wv][c[k]] + myoff[k];
    perm[pos] = i;
    s1p[pos] = v1[k];
    s2p[pos] = v2[k];
    clsc[pos >> 5] = c[k];  // benign same-value race within a chunk
  }
}

// ---- kD: Dp[jp] = sum_i exp2(lrelu(s1_i + s2_jp)) * exp(alpha*B[ci,cj]).
// 2 cols/thread, 512-row segments; class-uniform 32-chunks -> one weight per chunk.
__global__ __launch_bounds__(256) void kD(const float* __restrict__ s1p,
                                          const float* __restrict__ s2p,
                                          const int* __restrict__ clsc,
                                          const float* __restrict__ Bmat,
                                          const float* __restrict__ alpha_p,
                                          float* __restrict__ Dp) {
  __shared__ float EBT[256];   // EBT[a*16+b] = exp(alpha*B[a][b])
  __shared__ float s1s[512];
  __shared__ int clscs[16];
  int t = threadIdx.x;
  int rs = blockIdx.y;  // 512-row segment
  EBT[t] = __expf(alpha_p[0] * Bmat[t]);
  s1s[t] = s1p[rs * 512 + t];
  s1s[256 + t] = s1p[rs * 512 + 256 + t];
  if (t < 16) clscs[t] = clsc[rs * 16 + t];
  __syncthreads();
  int jp = blockIdx.x * 512 + t * 2;
  float s2a = s2p[jp], s2b = s2p[jp + 1];
  int cj = clsc[jp >> 5];  // jp, jp+1 in same chunk
  float acc0 = 0.f, acc1 = 0.f;
#pragma unroll 1
  for (int cc = 0; cc < 16; cc++) {
    float w = EBT[clscs[cc] * 16 + cj];
    float p0 = 0.f, p1 = 0.f;
#pragma unroll
    for (int r = 0; r < 32; r++) {
      float sv = s1s[cc * 32 + r];
      float x0 = sv + s2a, x1 = sv + s2b;
      p0 += fexp2(fmaxf(x0, 0.2f * x0));
      p1 += fexp2(fmaxf(x1, 0.2f * x1));
    }
    acc0 = fmaf(p0, w, acc0);
    acc1 = fmaf(p1, w, acc1);
  }
  atomicAdd(&Dp[jp], acc0);
  atomicAdd(&Dp[jp + 1], acc1);
}

// ---- kE: h2T[f][jp] = bf16( h[perm[jp]][f] / Dp[jp] ), 0 for pads ----
__global__ __launch_bounds__(256) void kE(const float* __restrict__ h,
                                          const float* __restrict__ Dp,
                                          const int* __restrict__ perm,
                                          unsigned short* __restrict__ h2T) {
  int t = threadIdx.x;
  int jp = blockIdx.x * 256 + t;
  int fq = blockIdx.y;  // 16 quads of 4 features
  int p = perm[jp];
  if (p < 0) {
#pragma unroll
    for (int k = 0; k < 4; k++) h2T[(size_t)(fq * 4 + k) * NP + jp] = 0;
  } else {
    float g = 1.0f / Dp[jp];
    float4 hv = *(const float4*)&h[p * FF + fq * 4];
    h2T[(size_t)(fq * 4 + 0) * NP + jp] = packbf1(g * hv.x);
    h2T[(size_t)(fq * 4 + 1) * NP + jp] = packbf1(g * hv.y);
    h2T[(size_t)(fq * 4 + 2) * NP + jp] = packbf1(g * hv.z);
    h2T[(size_t)(fq * 4 + 3) * NP + jp] = packbf1(g * hv.w);
  }
}

// ---- kF: U += E_tile @ h2T^T via MFMA; E generated in A-frag register layout ----
__global__ __launch_bounds__(256) void kF(const float* __restrict__ s1,
                                          const int* __restrict__ ci,
                                          const float* __restrict__ s2p,
                                          const int* __restrict__ clsc,
                                          const unsigned short* __restrict__ h2T,
                                          const float* __restrict__ Bmat,
                                          const float* __restrict__ alpha_p,
                                          float* __restrict__ U) {
  __shared__ float EBT2[256];  // EBT2[b*16+a] = exp(alpha*B[a][b])
  int t = threadIdx.x;
  int wave = t >> 6, lane = t & 63;
  int quad = lane >> 4, l16 = lane & 15;
  EBT2[t] = __expf(alpha_p[0] * Bmat[(t & 15) * 16 + (t >> 4)]);
  int row0 = blockIdx.x * 64 + wave * 16;
  float s1v = s1[row0 + l16];
  int civ = ci[row0 + l16];
  __syncthreads();

  f32x4 acc0 = {0.f, 0.f, 0.f, 0.f};
  f32x4 acc1 = {0.f, 0.f, 0.f, 0.f};
  f32x4 acc2 = {0.f, 0.f, 0.f, 0.f};
  f32x4 acc3 = {0.f, 0.f, 0.f, 0.f};

  int jbeg = blockIdx.y * (NP / 8);
  int jend = jbeg + (NP / 8);
  for (int j0 = jbeg; j0 < jend; j0 += 32) {
    int cch = clsc[j0 >> 5];                 // uniform -> scalar load
    float w = EBT2[cch * 16 + civ];
    float4 sa = *(const float4*)&s2p[j0 + quad * 8];
    float4 sb = *(const float4*)&s2p[j0 + quad * 8 + 4];
    float e0, e1, e2, e3, e4, e5, e6, e7, x;
    x = s1v + sa.x; e0 = fexp2(fmaxf(x, 0.2f * x)) * w;
    x = s1v + sa.y; e1 = fexp2(fmaxf(x, 0.2f * x)) * w;
    x = s1v + sa.z; e2 = fexp2(fmaxf(x, 0.2f * x)) * w;
    x = s1v + sa.w; e3 = fexp2(fmaxf(x, 0.2f * x)) * w;
    x = s1v + sb.x; e4 = fexp2(fmaxf(x, 0.2f * x)) * w;
    x = s1v + sb.y; e5 = fexp2(fmaxf(x, 0.2f * x)) * w;
    x = s1v + sb.z; e6 = fexp2(fmaxf(x, 0.2f * x)) * w;
    x = s1v + sb.w; e7 = fexp2(fmaxf(x, 0.2f * x)) * w;
    union { short8 s; unsigned int u[4]; } af;
    af.u[0] = packbf2(e0, e1);
    af.u[1] = packbf2(e2, e3);
    af.u[2] = packbf2(e4, e5);
    af.u[3] = packbf2(e6, e7);
    const unsigned short* bbase = h2T + (size_t)l16 * NP + j0 + quad * 8;
    short8 b0 = *(const short8*)(bbase);
    short8 b1 = *(const short8*)(bbase + 16 * NP);
    short8 b2 = *(const short8*)(bbase + 32 * NP);
    short8 b3 = *(const short8*)(bbase + 48 * NP);
    acc0 = __builtin_amdgcn_mfma_f32_16x16x32_bf16(af.s, b0, acc0, 0, 0, 0);
    acc1 = __builtin_amdgcn_mfma_f32_16x16x32_bf16(af.s, b1, acc1, 0, 0, 0);
    acc2 = __builtin_amdgcn_mfma_f32_16x16x32_bf16(af.s, b2, acc2, 0, 0, 0);
    acc3 = __builtin_amdgcn_mfma_f32_16x16x32_bf16(af.s, b3, acc3, 0, 0, 0);
  }
  // C layout: col = lane&15, row = quad*4 + reg
#pragma unroll
  for (int reg = 0; reg < 4; reg++) {
    int ro = (row0 + quad * 4 + reg) * FF + l16;
    atomicAdd(&U[ro + 0], acc0[reg]);
    atomicAdd(&U[ro + 16], acc1[reg]);
    atomicAdd(&U[ro + 32], acc2[reg]);
    atomicAdd(&U[ro + 48], acc3[reg]);
  }
}

// ---- kG: out = elu(U) ----
__global__ __launch_bounds__(256) void kG(const float* __restrict__ U, float* __restrict__ out) {
  int idx = blockIdx.x * 256 + threadIdx.x;
  float4 v = ((const float4*)U)[idx];
  v.x = v.x > 0.f ? v.x : __expf(v.x) - 1.f;
  v.y = v.y > 0.f ? v.y : __expf(v.y) - 1.f;
  v.z = v.z > 0.f ? v.z : __expf(v.z) - 1.f;
  v.w = v.w > 0.f ? v.w : __expf(v.w) - 1.f;
  ((float4*)out)[idx] = v;
}

extern "C" void kernel_launch(void* const* d_in, const int* in_sizes, int n_in,
                              void* d_out, int out_size, void* d_ws, size_t ws_size,
                              hipStream_t stream) {
  const float* in = (const float*)d_in[0];
  // d_in[1] = adj: all-ones, mathematically unused
  const float* W = (const float*)d_in[2];
  const float* a = (const float*)d_in[3];
  const float* Bmat = (const float*)d_in[4];
  const float* alpha = (const float*)d_in[5];
  const int* labels = (const int*)d_in[6];
  float* out = (float*)d_out;

  float* ws = (float*)d_ws;
  float* h = ws;                         // 524288
  float* U = h + 524288;                 // 524288
  float* s1 = U + 524288;                // 8192
  float* s2 = s1 + 8192;                 // 8192
  int* ci = (int*)(s2 + 8192);           // 8192
  float* s1p = (float*)(ci + 8192);      // 8704
  float* s2p = s1p + NP;                 // 8704
  float* Dp = s2p + NP;                  // 8704
  int* perm = (int*)(Dp + NP);           // 8704
  int* clsc = perm + NP;                 // 272
  int* pad = clsc + NCH;                 // 32 (alignment pad)
  unsigned short* h2T = (unsigned short*)(pad + 32);  // 64*8704 bf16 (16B-aligned)

  kZ<<<512, 256, 0, stream>>>((float4*)U, s1p, s2p, perm, Dp, clsc);
  kA<<<2048, 256, 0, stream>>>(in, W, a, labels, h, s1, s2, ci);
  kSort<<<1, 1024, 0, stream>>>(s1, s2, ci, perm, s1p, s2p, clsc);
  kD<<<dim3(17, 17), 256, 0, stream>>>(s1p, s2p, clsc, Bmat, alpha, Dp);
  kE<<<dim3(34, 16), 256, 0, stream>>>(h, Dp, perm, h2T);
  kF<<<dim3(128, 8), 256, 0, stream>>>(s1, ci, s2p, clsc, h2T, Bmat, alpha, U);
  kG<<<512, 256, 0, stream>>>(U, out);
}

// Round 5
// 427.523 us; speedup vs baseline: 3.7496x; 1.0083x over previous
//
#include <hip/hip_runtime.h>
#include <hip/hip_bf16.h>

#define NN 8192
#define FF 64
#define INF 48
#define NP 8704      // padded column count: 16 buckets, each 32-aligned
#define NCH (NP/32)  // 272 chunks
#define LOG2E 1.4426950408889634f

typedef __attribute__((ext_vector_type(8))) short short8;
typedef __attribute__((ext_vector_type(4))) float f32x4;

__device__ __forceinline__ float fexp2(float x) { return __builtin_amdgcn_exp2f(x); }

__device__ __forceinline__ unsigned int packbf2(float a, float b) {
  union { __hip_bfloat162 h2; unsigned int u; } c;
  c.h2 = __float22bfloat162_rn(float2{a, b});
  return c.u;
}
__device__ __forceinline__ unsigned short packbf1(float a) {
  union { __hip_bfloat16 h; unsigned short u; } c;
  c.h = __float2bfloat16(a);
  return c.u;
}
__device__ __forceinline__ float elu(float v) { return v > 0.f ? v : __expf(v) - 1.f; }

// ---- kA: h = in@W; s1,s2 (exp2 domain); class ci. Pure compute, no pad duty. ----
__global__ __launch_bounds__(256) void kA(const float* __restrict__ in,
                                          const float* __restrict__ W,
                                          const float* __restrict__ a,
                                          const int* __restrict__ labels,
                                          float* __restrict__ h,
                                          float* __restrict__ s1,
                                          float* __restrict__ s2,
                                          int* __restrict__ ci) {
  __shared__ float sIn[4][INF];
  int t = threadIdx.x;
  int w = t >> 6, lane = t & 63;
  int i = blockIdx.x * 4 + w;
  if (lane < INF) sIn[w][lane] = in[i * INF + lane];
  __syncthreads();
  float acc = 0.f;
#pragma unroll
  for (int k = 0; k < INF; k++) acc += sIn[w][k] * W[k * FF + lane];
  h[i * FF + lane] = acc;
  float v1 = acc * a[lane];
  float v2 = acc * a[FF + lane];
#pragma unroll
  for (int off = 32; off > 0; off >>= 1) {
    v1 += __shfl_xor(v1, off, 64);
    v2 += __shfl_xor(v2, off, 64);
  }
  if (lane == 0) {
    s1[i] = v1 * LOG2E;
    s2[i] = v2 * LOG2E;
    int c = labels[i] - 1;
    ci[i] = c < 0 ? 0 : (c > 15 ? 15 : c);
  }
}

// ---- kSort: single-block ballot-rank counting sort into 32-padded class buckets,
// plus all pad initialization (pads <= 512 entries). No global atomics.
__global__ __launch_bounds__(1024) void kSort(const float* __restrict__ s1,
                                              const float* __restrict__ s2,
                                              const int* __restrict__ ci,
                                              int* __restrict__ perm,
                                              float* __restrict__ s1p,
                                              float* __restrict__ s2p,
                                              int* __restrict__ clsc) {
  __shared__ int wcnt[16][16];   // [wave][cls]
  __shared__ int wbase[16][16];  // exclusive prefix over waves, per cls
  __shared__ int tot[16];
  __shared__ int cbase[17];      // 32-padded class starts; [16] = grand total S
  int t = threadIdx.x;
  int wv = t >> 6, lane = t & 63;
  unsigned long long lower = (1ULL << lane) - 1;
  int c[8], myoff[8];
  float v1[8], v2[8];
#pragma unroll
  for (int k = 0; k < 8; k++) {
    int i = wv * 512 + k * 64 + lane;
    c[k] = ci[i];
    v1[k] = s1[i];
    v2[k] = s2[i];
  }
#pragma unroll 1
  for (int cls = 0; cls < 16; cls++) {
    int run = 0;
#pragma unroll
    for (int k = 0; k < 8; k++) {
      unsigned long long m = __ballot(c[k] == cls);
      if (c[k] == cls) myoff[k] = run + __popcll(m & lower);
      run += __popcll(m);
    }
    if (lane == 0) wcnt[wv][cls] = run;
  }
  __syncthreads();
  if (t < 16) {  // t = class
    int s = 0;
    for (int w = 0; w < 16; w++) { wbase[w][t] = s; s += wcnt[w][t]; }
    tot[t] = s;
  }
  __syncthreads();
  if (t == 0) {
    int s = 0;
    for (int cls = 0; cls < 16; cls++) { cbase[cls] = s; s += (tot[cls] + 31) & ~31; }
    cbase[16] = s;
  }
  __syncthreads();
#pragma unroll
  for (int k = 0; k < 8; k++) {
    int i = wv * 512 + k * 64 + lane;
    int pos = cbase[c[k]] + wbase[wv][c[k]] + myoff[k];
    perm[pos] = i;
    s1p[pos] = v1[k];
    s2p[pos] = v2[k];
    clsc[pos >> 5] = c[k];  // benign same-value race within a chunk
  }
  // ---- pad fill: bucket tails ----
  int S = cbase[16];
#pragma unroll 1
  for (int cls = 0; cls < 16; cls++) {
    int start = cbase[cls] + tot[cls];
    int end = (cls < 15) ? cbase[cls + 1] : S;
    if (t < end - start) {
      int pos = start + t;
      perm[pos] = -1;
      s1p[pos] = -100.f;
      s2p[pos] = -100.f;
      clsc[pos >> 5] = cls;  // same value as real writers of this chunk
    }
  }
  // ---- tail beyond S (S is a multiple of 32) ----
  if (S + t < NP) {
    int pos = S + t;
    perm[pos] = -1;
    s1p[pos] = -100.f;
    s2p[pos] = -100.f;
  }
  if (t < NCH - (S >> 5)) clsc[(S >> 5) + t] = 0;
}

// ---- kDE: per 32-col chunk, complete column denominators (8-way row split,
// LDS reduce) then write this chunk's h2T slice: h2T[f][jp] = bf16(h[perm[jp]][f]/D).
// No global Dp, no atomics.
__global__ __launch_bounds__(256) void kDE(const float* __restrict__ s1p,
                                           const float* __restrict__ s2p,
                                           const int* __restrict__ clsc,
                                           const float* __restrict__ h,
                                           const int* __restrict__ perm,
                                           const float* __restrict__ Bmat,
                                           const float* __restrict__ alpha_p,
                                           unsigned short* __restrict__ h2T) {
  __shared__ float EBT[256];  // EBT[a*16+b] = exp(alpha*B[a][b])
  __shared__ int clsL[NCH];
  __shared__ float red[8][33];
  __shared__ float Dinv[32];
  __shared__ int permL[32];
  int t = threadIdx.x;
  int blk = blockIdx.x;  // chunk 0..271
  int jp0 = blk * 32;
  EBT[t] = __expf(alpha_p[0] * Bmat[t]);
  clsL[t] = clsc[t];
  if (t < NCH - 256) clsL[256 + t] = clsc[256 + t];
  if (t < 32) permL[t] = perm[jp0 + t];
  __syncthreads();
  int c = t & 31, rseg = t >> 5;  // 8 row segments of 1088
  float s2j = s2p[jp0 + c];
  int cj = clsL[blk];  // block-uniform
  float acc = 0.f;
#pragma unroll 1
  for (int ch = 0; ch < 34; ch++) {
    int chunk = rseg * 34 + ch;
    float w = EBT[clsL[chunk] * 16 + cj];
    int base = chunk * 32;
    float p = 0.f;
#pragma unroll
    for (int q = 0; q < 8; q++) {
      float4 sv = *(const float4*)&s1p[base + q * 4];
      float x0 = sv.x + s2j, x1 = sv.y + s2j, x2 = sv.z + s2j, x3 = sv.w + s2j;
      p += fexp2(fmaxf(x0, 0.2f * x0));
      p += fexp2(fmaxf(x1, 0.2f * x1));
      p += fexp2(fmaxf(x2, 0.2f * x2));
      p += fexp2(fmaxf(x3, 0.2f * x3));
    }
    acc = fmaf(p, w, acc);
  }
  red[rseg][c] = acc;
  __syncthreads();
  if (t < 32) {
    float s = 0.f;
#pragma unroll
    for (int r = 0; r < 8; r++) s += red[r][t];
    Dinv[t] = 1.0f / s;
  }
  __syncthreads();
  int p = permL[c];
  int fb = rseg * 8;  // 8 feature groups of 8
  if (p < 0) {
#pragma unroll
    for (int k = 0; k < 8; k++) h2T[(size_t)(fb + k) * NP + jp0 + c] = 0;
  } else {
    float g = Dinv[c];
    float4 h0 = *(const float4*)&h[p * FF + fb];
    float4 h1 = *(const float4*)&h[p * FF + fb + 4];
    h2T[(size_t)(fb + 0) * NP + jp0 + c] = packbf1(g * h0.x);
    h2T[(size_t)(fb + 1) * NP + jp0 + c] = packbf1(g * h0.y);
    h2T[(size_t)(fb + 2) * NP + jp0 + c] = packbf1(g * h0.z);
    h2T[(size_t)(fb + 3) * NP + jp0 + c] = packbf1(g * h0.w);
    h2T[(size_t)(fb + 4) * NP + jp0 + c] = packbf1(g * h1.x);
    h2T[(size_t)(fb + 5) * NP + jp0 + c] = packbf1(g * h1.y);
    h2T[(size_t)(fb + 6) * NP + jp0 + c] = packbf1(g * h1.z);
    h2T[(size_t)(fb + 7) * NP + jp0 + c] = packbf1(g * h1.w);
  }
}

// ---- kF2: out = elu(E @ h2T^T). 512 blocks x 16 rows; 4 waves split K in
// quarters; LDS reduce (stride-17); wave 0 applies elu and stores to out.
// E generated in A-frag register layout. No U buffer, no global atomics.
__global__ __launch_bounds__(256) void kF2(const float* __restrict__ s1,
                                           const int* __restrict__ ci,
                                           const float* __restrict__ s2p,
                                           const int* __restrict__ clsc,
                                           const unsigned short* __restrict__ h2T,
                                           const float* __restrict__ Bmat,
                                           const float* __restrict__ alpha_p,
                                           float* __restrict__ out) {
  __shared__ float EBT2[256];  // EBT2[b*16+a] = exp(alpha*B[a][b])
  __shared__ float red[3 * 1088];  // 3 waves x 64 lanes x 17 (pad)
  int t = threadIdx.x;
  int wv = t >> 6, lane = t & 63;
  int quad = lane >> 4, l16 = lane & 15;
  EBT2[t] = __expf(alpha_p[0] * Bmat[(t & 15) * 16 + (t >> 4)]);
  int row0 = blockIdx.x * 16;
  float s1v = s1[row0 + l16];
  int civ = ci[row0 + l16];
  __syncthreads();

  f32x4 acc0 = {0.f, 0.f, 0.f, 0.f};
  f32x4 acc1 = {0.f, 0.f, 0.f, 0.f};
  f32x4 acc2 = {0.f, 0.f, 0.f, 0.f};
  f32x4 acc3 = {0.f, 0.f, 0.f, 0.f};

  int jbeg = wv * (NP / 4);
  int jend = jbeg + (NP / 4);  // 68 chunks per wave
  for (int j0 = jbeg; j0 < jend; j0 += 32) {
    int cch = clsc[j0 >> 5];  // uniform -> scalar load
    float w = EBT2[cch * 16 + civ];
    float4 sa = *(const float4*)&s2p[j0 + quad * 8];
    float4 sb = *(const float4*)&s2p[j0 + quad * 8 + 4];
    float e0, e1, e2, e3, e4, e5, e6, e7, x;
    x = s1v + sa.x; e0 = fexp2(fmaxf(x, 0.2f * x)) * w;
    x = s1v + sa.y; e1 = fexp2(fmaxf(x, 0.2f * x)) * w;
    x = s1v + sa.z; e2 = fexp2(fmaxf(x, 0.2f * x)) * w;
    x = s1v + sa.w; e3 = fexp2(fmaxf(x, 0.2f * x)) * w;
    x = s1v + sb.x; e4 = fexp2(fmaxf(x, 0.2f * x)) * w;
    x = s1v + sb.y; e5 = fexp2(fmaxf(x, 0.2f * x)) * w;
    x = s1v + sb.z; e6 = fexp2(fmaxf(x, 0.2f * x)) * w;
    x = s1v + sb.w; e7 = fexp2(fmaxf(x, 0.2f * x)) * w;
    union { short8 s; unsigned int u[4]; } af;
    af.u[0] = packbf2(e0, e1);
    af.u[1] = packbf2(e2, e3);
    af.u[2] = packbf2(e4, e5);
    af.u[3] = packbf2(e6, e7);
    const unsigned short* bbase = h2T + (size_t)l16 * NP + j0 + quad * 8;
    short8 b0 = *(const short8*)(bbase);
    short8 b1 = *(const short8*)(bbase + 16 * NP);
    short8 b2 = *(const short8*)(bbase + 32 * NP);
    short8 b3 = *(const short8*)(bbase + 48 * NP);
    acc0 = __builtin_amdgcn_mfma_f32_16x16x32_bf16(af.s, b0, acc0, 0, 0, 0);
    acc1 = __builtin_amdgcn_mfma_f32_16x16x32_bf16(af.s, b1, acc1, 0, 0, 0);
    acc2 = __builtin_amdgcn_mfma_f32_16x16x32_bf16(af.s, b2, acc2, 0, 0, 0);
    acc3 = __builtin_amdgcn_mfma_f32_16x16x32_bf16(af.s, b3, acc3, 0, 0, 0);
  }
  if (wv > 0) {
    int base = (wv - 1) * 1088 + lane * 17;
#pragma unroll
    for (int reg = 0; reg < 4; reg++) {
      red[base + reg] = acc0[reg];
      red[base + 4 + reg] = acc1[reg];
      red[base + 8 + reg] = acc2[reg];
      red[base + 12 + reg] = acc3[reg];
    }
  }
  __syncthreads();
  if (wv == 0) {
    int base = lane * 17;
#pragma unroll
    for (int reg = 0; reg < 4; reg++) {
      float v0 = acc0[reg] + red[base + reg] + red[1088 + base + reg] + red[2176 + base + reg];
      float v1 = acc1[reg] + red[base + 4 + reg] + red[1088 + base + 4 + reg] + red[2176 + base + 4 + reg];
      float v2 = acc2[reg] + red[base + 8 + reg] + red[1088 + base + 8 + reg] + red[2176 + base + 8 + reg];
      float v3 = acc3[reg] + red[base + 12 + reg] + red[1088 + base + 12 + reg] + red[2176 + base + 12 + reg];
      int ro = (row0 + quad * 4 + reg) * FF + l16;
      out[ro + 0] = elu(v0);
      out[ro + 16] = elu(v1);
      out[ro + 32] = elu(v2);
      out[ro + 48] = elu(v3);
    }
  }
}

extern "C" void kernel_launch(void* const* d_in, const int* in_sizes, int n_in,
                              void* d_out, int out_size, void* d_ws, size_t ws_size,
                              hipStream_t stream) {
  const float* in = (const float*)d_in[0];
  // d_in[1] = adj: all-ones, mathematically unused
  const float* W = (const float*)d_in[2];
  const float* a = (const float*)d_in[3];
  const float* Bmat = (const float*)d_in[4];
  const float* alpha = (const float*)d_in[5];
  const int* labels = (const int*)d_in[6];
  float* out = (float*)d_out;

  float* ws = (float*)d_ws;
  float* h = ws;                       // 524288
  float* s1 = h + 524288;              // 8192
  float* s2 = s1 + 8192;               // 8192
  int* ci = (int*)(s2 + 8192);         // 8192
  float* s1p = (float*)(ci + 8192);    // NP
  float* s2p = s1p + NP;               // NP
  int* perm = (int*)(s2p + NP);        // NP
  int* clsc = perm + NP;               // NCH = 272
  int* pad = clsc + NCH;               // 16 (alignment)
  unsigned short* h2T = (unsigned short*)(pad + 16);  // 64*NP bf16, 16B-aligned

  kA<<<2048, 256, 0, stream>>>(in, W, a, labels, h, s1, s2, ci);
  kSort<<<1, 1024, 0, stream>>>(s1, s2, ci, perm, s1p, s2p, clsc);
  kDE<<<NCH, 256, 0, stream>>>(s1p, s2p, clsc, h, perm, Bmat, alpha, h2T);
  kF2<<<512, 256, 0, stream>>>(s1, ci, s2p, clsc, h2T, Bmat, alpha, out);
}